// Round 1
// baseline (1303.185 us; speedup 1.0000x reference)
//
#include <hip/hip_runtime.h>
#include <hip/hip_bf16.h>

#define S_TOK 8192
#define NEXP 64
#define NK 2048
#define CAP 256

// ---------------- zero-fill (1 GiB of f32) ----------------
__global__ __launch_bounds__(256) void fill_zero(float4* __restrict__ out, long long n4) {
    long long i = (long long)blockIdx.x * blockDim.x + threadIdx.x;
    long long stride = (long long)gridDim.x * blockDim.x;
    float4 z = make_float4(0.f, 0.f, 0.f, 0.f);
    for (; i < n4; i += stride) out[i] = z;
}

// ---------------- logits = x @ w^T  (f32, tiled) ----------------
// block: 256 threads, 64 tokens x 64 experts per block, Kc=64
__global__ __launch_bounds__(256) void gemm_logits(const float* __restrict__ x,
                                                   const float* __restrict__ w,
                                                   float* __restrict__ logits) {
    __shared__ float xs[64][65];
    __shared__ float ws[64][65];
    const int t = threadIdx.x;
    const int block_t0 = blockIdx.x * 64;
    const int te = (t & 15) * 4;   // expert base (0..60)
    const int tt = (t >> 4) * 4;   // token base within block (0..60)

    float acc[4][4];
#pragma unroll
    for (int i = 0; i < 4; ++i)
#pragma unroll
        for (int j = 0; j < 4; ++j) acc[i][j] = 0.f;

    for (int k0 = 0; k0 < NK; k0 += 64) {
        // stage 64x64 tiles of x and w; 256 threads x 4 float4 each
#pragma unroll
        for (int i = 0; i < 4; ++i) {
            int lin  = t + i * 256;        // float4 index 0..1023
            int row  = lin >> 4;           // 0..63
            int col4 = (lin & 15) * 4;     // 0..60
            float4 v = *reinterpret_cast<const float4*>(&x[(long long)(block_t0 + row) * NK + k0 + col4]);
            xs[row][col4 + 0] = v.x; xs[row][col4 + 1] = v.y;
            xs[row][col4 + 2] = v.z; xs[row][col4 + 3] = v.w;
            float4 u = *reinterpret_cast<const float4*>(&w[(long long)row * NK + k0 + col4]);
            ws[row][col4 + 0] = u.x; ws[row][col4 + 1] = u.y;
            ws[row][col4 + 2] = u.z; ws[row][col4 + 3] = u.w;
        }
        __syncthreads();
#pragma unroll
        for (int k = 0; k < 64; ++k) {
            float xv[4], wv[4];
#pragma unroll
            for (int i = 0; i < 4; ++i) xv[i] = xs[tt + i][k];
#pragma unroll
            for (int j = 0; j < 4; ++j) wv[j] = ws[te + j][k];
#pragma unroll
            for (int i = 0; i < 4; ++i)
#pragma unroll
                for (int j = 0; j < 4; ++j) acc[i][j] = fmaf(xv[i], wv[j], acc[i][j]);
        }
        __syncthreads();
    }
#pragma unroll
    for (int i = 0; i < 4; ++i)
#pragma unroll
        for (int j = 0; j < 4; ++j)
            logits[(long long)(block_t0 + tt + i) * NEXP + te + j] = acc[i][j];
}

// ---------------- per-token softmax max-gate + argmax ----------------
// one wave (64 lanes = 64 experts) per token; 4 tokens per 256-thread block
__global__ __launch_bounds__(256) void gate_argmax(const float* __restrict__ logits,
                                                   int* __restrict__ eidx,
                                                   float* __restrict__ gate) {
    const int lane = threadIdx.x & 63;
    const int tok = blockIdx.x * 4 + (threadIdx.x >> 6);
    float l = logits[(long long)tok * NEXP + lane];

    // wave argmax, lowest-index tie-break (matches jnp.argmax)
    float m = l; int mi = lane;
#pragma unroll
    for (int off = 32; off; off >>= 1) {
        float om  = __shfl_xor(m, off);
        int   omi = __shfl_xor(mi, off);
        if (om > m || (om == m && omi < mi)) { m = om; mi = omi; }
    }
    float e = expf(l - m);
    float s = e;
#pragma unroll
    for (int off = 32; off; off >>= 1) s += __shfl_xor(s, off);

    if (lane == 0) {
        eidx[tok] = mi;
        gate[tok] = 1.0f / s;   // softmax value at the argmax position
    }
}

// ---------------- capacity filter + scatter ----------------
// one wave per expert; sequential ballot-prefix over token order
__global__ __launch_bounds__(64) void cap_scatter(const int* __restrict__ eidx,
                                                  const float* __restrict__ gate,
                                                  float* __restrict__ out,
                                                  long long dispOff) {
    const int e = blockIdx.x;
    const int lane = threadIdx.x;
    int count = 0;
    for (int s0 = 0; s0 < S_TOK; s0 += 64) {
        int s = s0 + lane;
        bool match = (eidx[s] == e);
        unsigned long long b = __ballot(match);
        int rank = count + __popcll(b & ((1ull << lane) - 1ull));
        if (match && rank < CAP) {
            long long o = (long long)s * (NEXP * CAP) + (long long)e * CAP + rank;
            out[o] = gate[s];            // combine_weights
            out[dispOff + o] = 1.0f;     // dispatch_mask (bool -> 1.0f)
        }
        count += __popcll(b);
    }
}

extern "C" void kernel_launch(void* const* d_in, const int* in_sizes, int n_in,
                              void* d_out, int out_size, void* d_ws, size_t ws_size,
                              hipStream_t stream) {
    const float* x = (const float*)d_in[0];   // [8192, 2048]
    const float* w = (const float*)d_in[1];   // [64, 2048]
    float* out = (float*)d_out;               // combine [S,E,C] ++ dispatch [S,E,C]

    // workspace layout
    float* logits = (float*)d_ws;                                  // 8192*64*4 = 2 MiB
    int*   eidx   = (int*)((char*)d_ws + (size_t)S_TOK * NEXP * 4);  // 32 KiB
    float* gate   = (float*)((char*)eidx + (size_t)S_TOK * 4);       // 32 KiB

    const long long total = (long long)out_size;       // 268,435,456
    const long long dispOff = total / 2;               // 134,217,728

    // 1) zero-fill the 1 GiB output
    fill_zero<<<4096, 256, 0, stream>>>((float4*)out, total / 4);

    // 2) logits GEMM: 128 blocks x 64 tokens
    gemm_logits<<<S_TOK / 64, 256, 0, stream>>>(x, w, logits);

    // 3) softmax gate + argmax: 4 tokens per block
    gate_argmax<<<S_TOK / 4, 256, 0, stream>>>(logits, eidx, gate);

    // 4) capacity filter + scatter: one wave per expert
    cap_scatter<<<NEXP, 64, 0, stream>>>(eidx, gate, out, dispOff);
}